// Round 3
// baseline (523.710 us; speedup 1.0000x reference)
//
#include <hip/hip_runtime.h>
#include <stdint.h>

// AAM-Softmax fused: loss + acc for B=1024, C=100000, D=256.
//   K1: normalize emb rows (fp32) -> bf16 in MFMA-A fragment order (ws)
//   K2: grid (2 halves x 782 class-tiles). Per block: load+L2-normalize 128
//       weight rows -> bf16 register B-frags (so MFMA emits cos directly),
//       loop 32 M-tiles of its 512-row half: A-frags from L2-resident embf,
//       MFMA, clip/margin@target/exp(l-30) -> per-row sum+max(p) in LDS,
//       one coalesced partial slice out. No global atomics (R1 lesson:
//       200 MB write-through -> 818 us). M-split x2 raises grid to 6.1
//       blocks/CU (R2 lesson: occupancy 21% -> latency-bound at 285 us).
//   K3: reduce 782 partials/row (16 threads/row, coalesced), loss/acc, mean.
#define DIM    256
#define BATCH  1024
#define NCLS   100000
#define CBLK   128
#define NBLK   ((NCLS + CBLK - 1) / CBLK)   // 782 (96 padded classes: zero
                                            // frags -> p=2^-43, harmless)
#define CLIPV  0.9999999f               // 1 - 1e-7 (matches ref fp32 clip)
#define COSM   0.98006657784124163f     // cos(0.2)
#define SINM   0.19866933079506122f     // sin(0.2)
#define K30L2E 43.280851226668903f      // 30 * log2(e)

typedef __attribute__((ext_vector_type(8))) short  short8;   // 8 bf16 = 4 VGPR
typedef __attribute__((ext_vector_type(4))) float  floatx4;

// ws layout (~14 MB)
#define EMBF_OFF 0                      // 512 KB bf16 emb, fragment order
#define TL_OFF   (512 * 1024)           // 4 KB adjusted target cos per row
#define SP_OFF   (1u << 20)             // [2][782][512] f32 partial sumexp
#define MP_OFF   (8u << 20)             // [2][782][512] u32 partial max(p) bits

__device__ __forceinline__ unsigned short f2bf(float f) {
    unsigned u = __float_as_uint(f);
    u += 0x7fffu + ((u >> 16) & 1u);        // RNE; inputs are finite
    return (unsigned short)(u >> 16);
}

// ---------------- K1: normalize embeddings -> bf16 fragments ----------------
// 64 blocks x 256 threads; 16 lanes per row (R2 lesson: 4096-thread version
// was latency-bound).
__global__ __launch_bounds__(256) void k_norm_emb(
        const float* __restrict__ emb, unsigned short* __restrict__ embf) {
    const int tid = threadIdx.x;
    const int w = tid >> 6, l = tid & 63;
    const int r   = blockIdx.x * 16 + w * 4 + (l >> 4);   // global row
    const int l16 = l & 15;                               // 16 floats per lane
    const float* rp = emb + (size_t)r * DIM + l16 * 16;
    float v[16];
    float ss = 0.f;
#pragma unroll
    for (int i = 0; i < 4; ++i) {
        float4 a = *(const float4*)(rp + i * 4);
        v[i*4+0]=a.x; v[i*4+1]=a.y; v[i*4+2]=a.z; v[i*4+3]=a.w;
        ss += a.x*a.x + a.y*a.y + a.z*a.z + a.w*a.w;
    }
#pragma unroll
    for (int k = 1; k < 16; k <<= 1) ss += __shfl_xor(ss, k);  // within row grp
    const float sc = 1.f / fmaxf(sqrtf(ss), 1e-12f);
#pragma unroll
    for (int h = 0; h < 2; ++h) {          // two 8-element k-groups per lane
        const int g = 2 * l16 + h;         // k = 8g..8g+7
        const int s = g >> 2;              // frag chunk
        const int fl = (r & 15) + 16 * (g & 3);   // frag lane
        unsigned hh[8];
#pragma unroll
        for (int j = 0; j < 8; ++j) hh[j] = f2bf(v[h*8+j] * sc);
        uint4 u;
        u.x = hh[0] | (hh[1] << 16);
        u.y = hh[2] | (hh[3] << 16);
        u.z = hh[4] | (hh[5] << 16);
        u.w = hh[6] | (hh[7] << 16);
        *(uint4*)(embf + ((size_t)((r >> 4) * 8 + s) * 64 + fl) * 8) = u;
    }
}

// ---------------- K2: fused GEMM + online softmax partials ----------------
__global__ __launch_bounds__(256, 6) void k_main(
        const float* __restrict__ wgt, const int* __restrict__ labels,
        const unsigned short* __restrict__ embf,
        float* __restrict__ SP, unsigned* __restrict__ MP,
        float* __restrict__ TL) {
    __shared__ float    rs[512];                 // per-row sumexp accumulator
    __shared__ unsigned rm[512];                 // per-row max(p) bits
    __shared__ __align__(16) int llab[512];      // labels for this half
    const int half  = blockIdx.x;                // 0/1: rows half*512..+511
    const int ctile = blockIdx.y;
    const int tid = threadIdx.x;
    const int rowbase = half * 512;
    for (int i = tid; i < 512; i += 256) {
        rs[i] = 0.f; rm[i] = 0u; llab[i] = labels[rowbase + i];
    }
    const int w = tid >> 6, l = tid & 63;
    const int r16 = l & 15, q = l >> 4;
    const int cbase = ctile * CBLK + w * 32;     // wave owns 32 classes

    // --- stage B: L2-normalized bf16 weight fragments in regs ---
    // two-pass (norm then reload+scale+cast); 2nd pass hits L1.
    short8 bfrag[2][8];
#pragma unroll
    for (int ct = 0; ct < 2; ++ct) {
        const int cls = cbase + ct * 16 + r16;
        const float* rp = wgt + (size_t)cls * DIM + q * 8;
        float ss = 0.f;
        if (cls < NCLS) {
#pragma unroll
            for (int s = 0; s < 8; ++s) {
                float4 a = *(const float4*)(rp + 32 * s);
                float4 b = *(const float4*)(rp + 32 * s + 4);
                ss += a.x*a.x + a.y*a.y + a.z*a.z + a.w*a.w;
                ss += b.x*b.x + b.y*b.y + b.z*b.z + b.w*b.w;
            }
        }
        ss += __shfl_xor(ss, 16);      // quads of a class are OOB together
        ss += __shfl_xor(ss, 32);
        const float sc = 1.f / fmaxf(sqrtf(ss), 1e-12f);
        if (cls < NCLS) {
#pragma unroll
            for (int s = 0; s < 8; ++s) {
                float4 a = *(const float4*)(rp + 32 * s);
                float4 b = *(const float4*)(rp + 32 * s + 4);
                bfrag[ct][s][0] = (short)f2bf(a.x * sc);
                bfrag[ct][s][1] = (short)f2bf(a.y * sc);
                bfrag[ct][s][2] = (short)f2bf(a.z * sc);
                bfrag[ct][s][3] = (short)f2bf(a.w * sc);
                bfrag[ct][s][4] = (short)f2bf(b.x * sc);
                bfrag[ct][s][5] = (short)f2bf(b.y * sc);
                bfrag[ct][s][6] = (short)f2bf(b.z * sc);
                bfrag[ct][s][7] = (short)f2bf(b.w * sc);
            }
        } else {
#pragma unroll
            for (int s = 0; s < 8; ++s)
#pragma unroll
                for (int j = 0; j < 8; ++j) bfrag[ct][s][j] = 0;
        }
    }

    __syncthreads();                   // LDS init visible to all waves

    // --- M loop: 32 tiles of 16 rows of this half, barrier-free ---
    const short8* ap = (const short8*)embf + (size_t)half * 16384 + l;
    for (int mt = 0; mt < 32; ++mt, ap += 512) {
        short8 af[8];
#pragma unroll
        for (int s = 0; s < 8; ++s) af[s] = ap[s * 64];   // L2-broadcast hits
        floatx4 acc0 = {0.f, 0.f, 0.f, 0.f};
        floatx4 acc1 = {0.f, 0.f, 0.f, 0.f};
#pragma unroll
        for (int s = 0; s < 8; ++s) {
            acc0 = __builtin_amdgcn_mfma_f32_16x16x32_bf16(af[s], bfrag[0][s], acc0, 0, 0, 0);
            acc1 = __builtin_amdgcn_mfma_f32_16x16x32_bf16(af[s], bfrag[1][s], acc1, 0, 0, 0);
        }
        const int mloc = mt * 16;                  // row-local base
        const int4 lb = *(const int4*)&llab[mloc + q * 4];
        const int lbl[4] = {lb.x, lb.y, lb.z, lb.w};
        float sum[4] = {0.f, 0.f, 0.f, 0.f};
        float mx[4]  = {0.f, 0.f, 0.f, 0.f};       // max of p (monotone in t)
#pragma unroll
        for (int ct = 0; ct < 2; ++ct) {
            const int cls = cbase + ct * 16 + r16;
#pragma unroll
            for (int r = 0; r < 4; ++r) {
                float t = ct ? acc1[r] : acc0[r];            // cos(theta)
                t = fminf(fmaxf(t, -CLIPV), CLIPV);          // v_med3
                if (__builtin_expect(cls == lbl[r], 0)) {    // margin @ target
                    t = t * COSM - sqrtf(fmaxf(1.f - t * t, 0.f)) * SINM;
                    TL[rowbase + mloc + q * 4 + r] = t;
                }
                const float p = exp2f(fmaf(t, K30L2E, -K30L2E));
                sum[r] += p;
                mx[r] = fmaxf(mx[r], p);
            }
        }
#pragma unroll
        for (int k = 1; k < 16; k <<= 1) {      // reduce over 16 cols/quad
#pragma unroll
            for (int r = 0; r < 4; ++r) {
                sum[r] += __shfl_xor(sum[r], k);
                mx[r] = fmaxf(mx[r], __shfl_xor(mx[r], k));
            }
        }
        if (r16 < 4) {
            float sv = sum[0], mv = mx[0];
            if (r16 == 1) { sv = sum[1]; mv = mx[1]; }
            else if (r16 == 2) { sv = sum[2]; mv = mx[2]; }
            else if (r16 == 3) { sv = sum[3]; mv = mx[3]; }
            const int row = mloc + q * 4 + r16;
            atomicAdd(&rs[row], sv);                    // ds_add, 4-way max
            atomicMax(&rm[row], __float_as_uint(mv));   // p>0 -> bit-monotone
        }
    }

    __syncthreads();
    // one contention-free, coalesced partial slice per block
    float*    sp = SP + ((size_t)half * NBLK + ctile) * 512;
    unsigned* mp = MP + ((size_t)half * NBLK + ctile) * 512;
    for (int i = tid; i < 512; i += 256) { sp[i] = rs[i]; mp[i] = rm[i]; }
}

// ---------------- K3: reduce partials + per-row loss/acc + mean ----------------
// 64 blocks x 256 threads; 16 threads per row, coalesced 64B-group reads.
__global__ __launch_bounds__(256) void k_final(
        const float* __restrict__ SP, const unsigned* __restrict__ MP,
        const float* __restrict__ TL, float* __restrict__ out) {
    __shared__ float    ls[16][16];
    __shared__ unsigned lm[16][16];
    const int tid = threadIdx.x;
    const int r16 = tid & 15;                 // row within block
    const int c   = tid >> 4;                 // partial-chunk lane
    const int row = blockIdx.x * 16 + r16;
    const int half = row >> 9, ri = row & 511;
    const float*    spb = SP + (size_t)half * NBLK * 512 + ri;
    const unsigned* mpb = MP + (size_t)half * NBLK * 512 + ri;
    float s = 0.f;
    unsigned m = 0u;
    for (int b = c; b < NBLK; b += 16) {      // 16 consecutive rows/line ✓
        s += spb[(size_t)b * 512];
        const unsigned v = mpb[(size_t)b * 512];
        m = v > m ? v : m;
    }
    ls[c][r16] = s; lm[c][r16] = m;
    __syncthreads();
    float loss = 0.f, corr = 0.f;
    if (tid < 16) {
        float st = 0.f; unsigned mt = 0u;
#pragma unroll
        for (int i = 0; i < 16; ++i) {
            st += ls[i][tid];
            mt = lm[i][tid] > mt ? lm[i][tid] : mt;
        }
        const float tl = TL[blockIdx.x * 16 + tid];
        loss = 30.f + logf(st) - 30.f * tl;   // logsumexp - target logit
        const float padj = exp2f(fmaf(tl, K30L2E, -K30L2E));  // == K2's p
        corr = (__float_as_uint(padj) >= mt) ? 1.f : 0.f;
    }
#pragma unroll
    for (int k = 1; k < 16; k <<= 1) {        // lanes 16..63 carry zeros
        loss += __shfl_xor(loss, k);
        corr += __shfl_xor(corr, k);
    }
    if (tid == 0) {
        atomicAdd(out + 0, loss * (1.f / 1024.f));
        atomicAdd(out + 1, corr * (1.f / 1024.f));
    }
}

extern "C" void kernel_launch(void* const* d_in, const int* in_sizes, int n_in,
                              void* d_out, int out_size, void* d_ws, size_t ws_size,
                              hipStream_t stream) {
    (void)in_sizes; (void)n_in; (void)out_size; (void)ws_size;
    const float* emb    = (const float*)d_in[0];
    const float* wgt    = (const float*)d_in[1];
    const int*   labels = (const int*)d_in[2];
    char* ws = (char*)d_ws;
    unsigned short* embf = (unsigned short*)(ws + EMBF_OFF);
    float*    TL = (float*)(ws + TL_OFF);
    float*    SP = (float*)(ws + SP_OFF);
    unsigned* MP = (unsigned*)(ws + MP_OFF);

    hipMemsetAsync(d_out, 0, 2 * sizeof(float), stream);  // K3 accumulates
    k_norm_emb<<<64, 256, 0, stream>>>(emb, embf);
    k_main<<<dim3(2, NBLK), 256, 0, stream>>>(wgt, labels, embf, SP, MP, TL);
    k_final<<<64, 256, 0, stream>>>(SP, MP, TL, (float*)d_out);
}

// Round 4
// 316.963 us; speedup vs baseline: 1.6523x; 1.6523x over previous
//
#include <hip/hip_runtime.h>
#include <stdint.h>

// AAM-Softmax fused: loss + acc for B=1024, C=100000, D=256.
//   K0/K1 (k_norm): L2-normalize rows fp32 -> bf16 in MFMA fragment order,
//       run once for weight (100352 padded classes) and once for emb.
//   K2 (k_main): rows OUTER / classes INNER. grid (8 row-groups x 96
//       class-groups). Wave holds 32 rows' A-frags + labels in registers,
//       streams 66 bf16 B-tiles from L3-resident wgtf, accumulates per-row
//       sumexp/max in REGISTERS across the whole class loop (R2 lesson: the
//       per-tile butterfly+LDS-atomic was ~77us of VALU; now one butterfly
//       per wave). Weight traffic = 8 x 51 MB bf16 from L3 (R3 lesson:
//       810 MB of fp32 re-reads thrashed L3 -> 729 MB HBM -> 408 us).
//   K3 (k_final): reduce 96 partials/row, loss/acc, mean.
#define DIM    256
#define BATCH  1024
#define NCLS   100000
#define NCT    96                      // class groups
#define TPG    66                      // 16-class tiles per group
#define NCLS_PAD (NCT * TPG * 16)      // 101376; pads are zero-frags ->
                                       // p=2^-43 each, ~2e-3 relative on S
#define RG     8                       // row groups
#define RPB    128                     // rows per block (4 waves x 32)
#define CLIPV  0.9999999f              // 1 - 1e-7 (matches ref fp32 clip)
#define COSM   0.98006657784124163f    // cos(0.2)
#define SINM   0.19866933079506122f    // sin(0.2)
#define K30L2E 43.280851226668903f     // 30 * log2(e)

typedef __attribute__((ext_vector_type(8))) short  short8;   // 8 bf16 = 4 VGPR
typedef __attribute__((ext_vector_type(4))) float  floatx4;

// ws layout (~51.3 MB)
#define EMBF_OFF 0                                  // 512 KB bf16 emb frags
#define TL_OFF   (512 * 1024)                       // 4 KB target cos/row
#define WGTF_OFF (1024 * 1024)                      // 49.5 MB bf16 wgt frags
#define SP_OFF   (WGTF_OFF + (size_t)NCLS_PAD * DIM * 2)   // 96x1024 f32
#define MP_OFF   (SP_OFF + (size_t)NCT * BATCH * 4)        // 96x1024 u32

__device__ __forceinline__ unsigned short f2bf(float f) {
    unsigned u = __float_as_uint(f);
    u += 0x7fffu + ((u >> 16) & 1u);        // RNE; inputs are finite
    return (unsigned short)(u >> 16);
}

// ---------- K0/K1: L2-normalize rows -> bf16 MFMA fragments ----------
// 16 rows per block, 16 lanes/row. Rows >= nvalid write zeros (pad classes).
__global__ __launch_bounds__(256) void k_norm(
        const float* __restrict__ src, unsigned short* __restrict__ dst,
        int nvalid) {
    const int tid = threadIdx.x;
    const int w = tid >> 6, l = tid & 63;
    const int r   = blockIdx.x * 16 + w * 4 + (l >> 4);
    const int l16 = l & 15;                               // 16 floats/lane
    float v[16];
    float ss = 0.f;
    if (r < nvalid) {
        const float* rp = src + (size_t)r * DIM + l16 * 16;
#pragma unroll
        for (int i = 0; i < 4; ++i) {
            float4 a = *(const float4*)(rp + i * 4);
            v[i*4+0]=a.x; v[i*4+1]=a.y; v[i*4+2]=a.z; v[i*4+3]=a.w;
            ss += a.x*a.x + a.y*a.y + a.z*a.z + a.w*a.w;
        }
    } else {
#pragma unroll
        for (int i = 0; i < 16; ++i) v[i] = 0.f;
    }
#pragma unroll
    for (int k = 1; k < 16; k <<= 1) ss += __shfl_xor(ss, k);
    const float sc = 1.f / fmaxf(sqrtf(ss), 1e-12f);
#pragma unroll
    for (int h = 0; h < 2; ++h) {          // two 8-element k-groups per lane
        const int g = 2 * l16 + h;         // k = 8g..8g+7
        const int s = g >> 2;              // k-chunk 0..7
        const int fl = (r & 15) + 16 * (g & 3);   // fragment lane
        unsigned hh[8];
#pragma unroll
        for (int j = 0; j < 8; ++j) hh[j] = f2bf(v[h*8+j] * sc);
        uint4 u;
        u.x = hh[0] | (hh[1] << 16);
        u.y = hh[2] | (hh[3] << 16);
        u.z = hh[4] | (hh[5] << 16);
        u.w = hh[6] | (hh[7] << 16);
        *(uint4*)(dst + ((size_t)((r >> 4) * 8 + s) * 64 + fl) * 8) = u;
    }
}

// ---------------- K2: fused GEMM + register-resident softmax partials -------
__global__ __launch_bounds__(256, 3) void k_main(
        const unsigned short* __restrict__ wgtf, const int* __restrict__ labels,
        const unsigned short* __restrict__ embf,
        float* __restrict__ SP, unsigned* __restrict__ MP,
        float* __restrict__ TL) {
    const int tid = threadIdx.x;
    const int w = tid >> 6, l = tid & 63;
    const int r16 = l & 15, q = l >> 4;
    const int rowbase = blockIdx.x * RPB + w * 32;   // wave's 32 rows
    const int cg = blockIdx.y;                       // class group 0..95

    // A-fragments for 2 M-tiles, held in registers the whole kernel
    short8 af[2][8];
    {
        const short8* ap = (const short8*)embf + ((size_t)(rowbase >> 4) * 8) * 64 + l;
#pragma unroll
        for (int mt = 0; mt < 2; ++mt)
#pragma unroll
            for (int s = 0; s < 8; ++s) af[mt][s] = ap[(mt * 8 + s) * 64];
    }
    int lbl[2][4];
#pragma unroll
    for (int mt = 0; mt < 2; ++mt)
#pragma unroll
        for (int r = 0; r < 4; ++r)
            lbl[mt][r] = labels[rowbase + mt * 16 + q * 4 + r];

    float sum[2][4] = {{0.f,0.f,0.f,0.f},{0.f,0.f,0.f,0.f}};
    float mx [2][4] = {{0.f,0.f,0.f,0.f},{0.f,0.f,0.f,0.f}};  // max of p

    const short8* bp = (const short8*)wgtf + ((size_t)(cg * TPG) * 8) * 64 + l;
    for (int t = 0; t < TPG; ++t, bp += 512) {
        short8 bf[8];
#pragma unroll
        for (int s = 0; s < 8; ++s) bf[s] = bp[s * 64];  // 1KB/instr coalesced
        const int cls = (cg * TPG + t) * 16 + r16;       // lane's class column
#pragma unroll
        for (int mt = 0; mt < 2; ++mt) {
            floatx4 acc = {0.f, 0.f, 0.f, 0.f};
#pragma unroll
            for (int s = 0; s < 8; ++s)
                acc = __builtin_amdgcn_mfma_f32_16x16x32_bf16(af[mt][s], bf[s], acc, 0, 0, 0);
#pragma unroll
            for (int r = 0; r < 4; ++r) {
                float tt = fminf(fmaxf(acc[r], -CLIPV), CLIPV);  // cos(theta)
                if (__builtin_expect(cls == lbl[mt][r], 0)) {    // margin @ target
                    tt = tt * COSM - sqrtf(fmaxf(1.f - tt * tt, 0.f)) * SINM;
                    TL[rowbase + mt * 16 + q * 4 + r] = tt;
                }
                const float p = exp2f(fmaf(tt, K30L2E, -K30L2E));
                sum[mt][r] += p;                 // register accumulation —
                mx[mt][r] = fmaxf(mx[mt][r], p); // no per-tile reduction!
            }
        }
    }

    // one butterfly per wave (over the 16 class-columns)
#pragma unroll
    for (int k = 1; k < 16; k <<= 1)
#pragma unroll
        for (int mt = 0; mt < 2; ++mt)
#pragma unroll
            for (int r = 0; r < 4; ++r) {
                sum[mt][r] += __shfl_xor(sum[mt][r], k);
                mx[mt][r] = fmaxf(mx[mt][r], __shfl_xor(mx[mt][r], k));
            }
    if (r16 < 4) {
#pragma unroll
        for (int mt = 0; mt < 2; ++mt) {
            float sv = sum[mt][0], mv = mx[mt][0];
            if (r16 == 1) { sv = sum[mt][1]; mv = mx[mt][1]; }
            else if (r16 == 2) { sv = sum[mt][2]; mv = mx[mt][2]; }
            else if (r16 == 3) { sv = sum[mt][3]; mv = mx[mt][3]; }
            const int row = rowbase + mt * 16 + q * 4 + r16;
            SP[cg * BATCH + row] = sv;
            MP[cg * BATCH + row] = __float_as_uint(mv);
        }
    }
}

// ---------------- K3: reduce partials + per-row loss/acc + mean -------------
__global__ __launch_bounds__(256) void k_final(
        const float* __restrict__ SP, const unsigned* __restrict__ MP,
        const float* __restrict__ TL, float* __restrict__ out) {
    __shared__ float    ls[16][16];
    __shared__ unsigned lm[16][16];
    const int tid = threadIdx.x;
    const int r16 = tid & 15;                 // row within block
    const int c   = tid >> 4;                 // partial-chunk lane
    const int row = blockIdx.x * 16 + r16;
    float s = 0.f;
    unsigned m = 0u;
    for (int b = c; b < NCT; b += 16) {       // 6 iters, 64B-coalesced
        s += SP[(size_t)b * BATCH + row];
        const unsigned v = MP[(size_t)b * BATCH + row];
        m = v > m ? v : m;
    }
    ls[c][r16] = s; lm[c][r16] = m;
    __syncthreads();
    float loss = 0.f, corr = 0.f;
    if (tid < 16) {
        float st = 0.f; unsigned mt = 0u;
#pragma unroll
        for (int i = 0; i < 16; ++i) {
            st += ls[i][tid];
            mt = lm[i][tid] > mt ? lm[i][tid] : mt;
        }
        const float tl = TL[blockIdx.x * 16 + tid];
        loss = 30.f + logf(st) - 30.f * tl;   // logsumexp - target logit
        const float padj = exp2f(fmaf(tl, K30L2E, -K30L2E));  // == K2's p
        corr = (__float_as_uint(padj) >= mt) ? 1.f : 0.f;
    }
#pragma unroll
    for (int k = 1; k < 16; k <<= 1) {        // lanes 16..63 carry zeros
        loss += __shfl_xor(loss, k);
        corr += __shfl_xor(corr, k);
    }
    if (tid == 0) {
        atomicAdd(out + 0, loss * (1.f / 1024.f));
        atomicAdd(out + 1, corr * (1.f / 1024.f));
    }
}

extern "C" void kernel_launch(void* const* d_in, const int* in_sizes, int n_in,
                              void* d_out, int out_size, void* d_ws, size_t ws_size,
                              hipStream_t stream) {
    (void)in_sizes; (void)n_in; (void)out_size; (void)ws_size;
    const float* emb    = (const float*)d_in[0];
    const float* wgt    = (const float*)d_in[1];
    const int*   labels = (const int*)d_in[2];
    char* ws = (char*)d_ws;
    unsigned short* embf = (unsigned short*)(ws + EMBF_OFF);
    unsigned short* wgtf = (unsigned short*)(ws + WGTF_OFF);
    float*    TL = (float*)(ws + TL_OFF);
    float*    SP = (float*)(ws + SP_OFF);
    unsigned* MP = (unsigned*)(ws + MP_OFF);

    hipMemsetAsync(d_out, 0, 2 * sizeof(float), stream);  // K3 accumulates
    k_norm<<<BATCH / 16, 256, 0, stream>>>(emb, embf, BATCH);
    k_norm<<<NCLS_PAD / 16, 256, 0, stream>>>(wgt, wgtf, NCLS);
    k_main<<<dim3(RG, NCT), 256, 0, stream>>>(wgtf, labels, embf, SP, MP, TL);
    k_final<<<64, 256, 0, stream>>>(SP, MP, TL, (float*)d_out);
}